// Round 1
// baseline (737.216 us; speedup 1.0000x reference)
//
#include <hip/hip_runtime.h>

// Problem: N=50000 nodes, D=128, E=625000 edges, 2 node classes, 2 edge classes.
// Outputs concatenated flat in d_out (float32):
//   out0 = x                      [N,128]
//   out1 = concat(x[src],x[dst])  [E,256]
//   out2 = x@Wn + bn              [N,2]
//   out3 = out1@We + be           [E,2]
//
// Key algebraic restructure vs previous version:
//   out1@We == x[src]@We_top + x[dst]@We_bot
// so per-node partials y[n] = {x[n]@We_top (2), x[n]@We_bot (2)} are precomputed
// once in the node pass (800 KB, L2-resident), and the edge pass becomes a pure
// gather-copy plus an 8-B-gather logits pass. The 12-bpermute serial reduce per
// edge is gone entirely.

#define GCN_D 128
#define EPB 256   // edges per block chunk in the edge-copy kernel

typedef float f32x4 __attribute__((ext_vector_type(4)));

// One 32-lane half-wave per node row. Copies x -> out0, computes node_x -> out2,
// and the per-node edge partials y[n] = {t0,t1,b0,b1} -> workspace.
__global__ void gcn_node_kernel(const float4* __restrict__ x4,
                                const float4* __restrict__ Wn4,  // 128*2 floats = 64 float4
                                const float* __restrict__ bn,
                                const float4* __restrict__ We4,  // 256*2 floats = 128 float4
                                float4* __restrict__ out0,
                                float2* __restrict__ out2,
                                float4* __restrict__ y,          // [N] {t0,t1,b0,b1}; may be null
                                int N) {
    int gtid = blockIdx.x * blockDim.x + threadIdx.x;
    int node = gtid >> 5;          // 32 lanes per node
    int l    = gtid & 31;          // float4 index within the 128-float row
    if (node >= N) return;

    float4 v = x4[(size_t)node * 32 + l];
    out0[(size_t)node * 32 + l] = v;

    // Wn [128,2] row-major: lane l covers rows 4l..4l+3 -> float4 2l, 2l+1.
    float4 na = Wn4[2 * l],      nb = Wn4[2 * l + 1];
    // We [256,2] row-major: top rows k=4l..4l+3 -> float4 2l,2l+1;
    //                       bottom rows 128+4l.. -> float4 64+2l, 64+2l+1.
    float4 ta = We4[2 * l],      tb = We4[2 * l + 1];
    float4 ba = We4[64 + 2 * l], bb = We4[64 + 2 * l + 1];

    float n0 = v.x * na.x + v.y * na.z + v.z * nb.x + v.w * nb.z;
    float n1 = v.x * na.y + v.y * na.w + v.z * nb.y + v.w * nb.w;
    float t0 = v.x * ta.x + v.y * ta.z + v.z * tb.x + v.w * tb.z;
    float t1 = v.x * ta.y + v.y * ta.w + v.z * tb.y + v.w * tb.w;
    float b0 = v.x * ba.x + v.y * ba.z + v.z * bb.x + v.w * bb.z;
    float b1 = v.x * ba.y + v.y * ba.w + v.z * bb.y + v.w * bb.w;

    for (int m = 16; m >= 1; m >>= 1) {
        n0 += __shfl_xor(n0, m, 32);
        n1 += __shfl_xor(n1, m, 32);
        t0 += __shfl_xor(t0, m, 32);
        t1 += __shfl_xor(t1, m, 32);
        b0 += __shfl_xor(b0, m, 32);
        b1 += __shfl_xor(b1, m, 32);
    }
    if (l == 0) {
        out2[node] = make_float2(n0 + bn[0], n1 + bn[1]);
        if (y) y[node] = make_float4(t0, t1, b0, b1);
    }
}

// Fast edge pass: pure gather-copy + tiny logits.
// Each block owns a contiguous chunk of EPB edges:
//   1) stage the 2*EPB indices into LDS (coalesced) and, with the indices still
//      in registers, compute out3 = y[src].xy + y[dst].zw + be (8-B gathers,
//      y is L2-resident).
//   2) 4 waves loop over the chunk; half-wave per row: lanes<32 copy x[src],
//      lanes>=32 copy x[dst]; 16 B/lane, nt store (out1 is never re-read --
//      don't evict x from L2/L3).
__global__ void gcn_edge_copy(const float4* __restrict__ x4,
                              const int* __restrict__ eidx,     // [2,E] int32
                              const float4* __restrict__ y,     // [N] {t0,t1,b0,b1}
                              const float* __restrict__ be,
                              float4* __restrict__ out1,
                              float2* __restrict__ out3,
                              int E, int nchunks) {
    __shared__ int s_src[EPB];
    __shared__ int s_dst[EPB];
    int tid  = threadIdx.x;        // 256
    int lane = tid & 63;
    int wv   = tid >> 6;           // wave id 0..3
    int col  = lane & 31;
    int half = lane >> 5;          // 0 = src row, 1 = dst row
    float b0 = be[0], b1 = be[1];

    for (int chunk = blockIdx.x; chunk < nchunks; chunk += gridDim.x) {
        int base = chunk * EPB;
        int n = min(EPB, E - base);
        __syncthreads();                    // protect s_* reuse across chunks
        if (tid < n) {
            int s = eidx[base + tid];
            int d = eidx[E + base + tid];
            s_src[tid] = s;
            s_dst[tid] = d;
            float4 ys = y[s];
            float4 yd = y[d];
            out3[base + tid] = make_float2(ys.x + yd.z + b0, ys.y + yd.w + b1);
        }
        __syncthreads();
        #pragma unroll 4
        for (int i = wv; i < n; i += 4) {
            int row = half ? s_dst[i] : s_src[i];
            f32x4 v = ((const f32x4*)x4)[(size_t)row * 32 + col];
            __builtin_nontemporal_store(
                v, (f32x4*)&out1[((size_t)(base + i)) * 64 + lane]);
        }
    }
}

// Fallback (ws too small): previous harness-verified edge kernel.
// One 64-lane wave per edge; full in-wave reduce for out3.
__global__ void gcn_edge_kernel(const float4* __restrict__ x4,
                                const int* __restrict__ eidx,
                                const float4* __restrict__ We4,
                                const float* __restrict__ be,
                                float4* __restrict__ out1,
                                float2* __restrict__ out3,
                                int E) {
    int lane  = threadIdx.x & 63;
    int wave  = (blockIdx.x * blockDim.x + threadIdx.x) >> 6;
    int nwave = (gridDim.x * blockDim.x) >> 6;

    float4 wa = We4[2 * lane];
    float4 wb = We4[2 * lane + 1];
    float b0 = be[0], b1 = be[1];
    int col = lane & 31;

    for (int e = wave; e < E; e += nwave) {
        int row = (lane < 32) ? eidx[e] : eidx[E + e];
        float4 v = x4[(size_t)row * 32 + col];
        out1[(size_t)e * 64 + lane] = v;

        float p0 = v.x * wa.x + v.y * wa.z + v.z * wb.x + v.w * wb.z;
        float p1 = v.x * wa.y + v.y * wa.w + v.z * wb.y + v.w * wb.w;
        for (int m = 32; m >= 1; m >>= 1) {
            p0 += __shfl_xor(p0, m);
            p1 += __shfl_xor(p1, m);
        }
        if (lane == 0) out3[e] = make_float2(p0 + b0, p1 + b1);
    }
}

extern "C" void kernel_launch(void* const* d_in, const int* in_sizes, int n_in,
                              void* d_out, int out_size, void* d_ws, size_t ws_size,
                              hipStream_t stream) {
    const float* x   = (const float*)d_in[0];
    const int* eidx  = (const int*)d_in[1];
    const float* Wn  = (const float*)d_in[2];
    const float* bn  = (const float*)d_in[3];
    const float* We  = (const float*)d_in[4];
    const float* be  = (const float*)d_in[5];

    const int N = in_sizes[0] / GCN_D;   // 50000
    const int E = in_sizes[1] / 2;       // 625000

    float* out  = (float*)d_out;
    float* out0 = out;                                   // [N,128]
    float* out1 = out0 + (size_t)N * GCN_D;              // [E,256]
    float* out2 = out1 + (size_t)E * 2 * GCN_D;          // [N,2]
    float* out3 = out2 + (size_t)N * 2;                  // [E,2]

    size_t y_bytes = (size_t)N * sizeof(float4);         // 800 KB
    float4* y = (d_ws && ws_size >= y_bytes) ? (float4*)d_ws : nullptr;

    // Node pass: 32 threads per node; also produces y (edge logit partials).
    {
        int threads = 256;
        int blocks = (N * 32 + threads - 1) / threads;   // 6250
        gcn_node_kernel<<<blocks, threads, 0, stream>>>(
            (const float4*)x, (const float4*)Wn, bn, (const float4*)We,
            (float4*)out0, (float2*)out2, y, N);
    }

    if (y) {
        // Fast path: pure gather-copy + 8-B-gather logits.
        int nchunks = (E + EPB - 1) / EPB;               // 2442
        gcn_edge_copy<<<nchunks, 256, 0, stream>>>(
            (const float4*)x, eidx, y, be,
            (float4*)out1, (float2*)out3, E, nchunks);
    } else {
        // Fallback: previous verified kernel.
        gcn_edge_kernel<<<8192, 256, 0, stream>>>(
            (const float4*)x, eidx, (const float4*)We, be,
            (float4*)out1, (float2*)out3, E);
    }
}